// Round 13
// baseline (148.077 us; speedup 1.0000x reference)
//
#include <hip/hip_runtime.h>
#include <cstdint>
#include <cstddef>

// MHA: B=2, S=2048, D=1024, H=16, DK=DV=64, causal.
// Pipeline: prep (W->bf16 W^T + Q/K/V fp32->bf16) ; projection GEMMs
// (global_load_lds; Q pre-scaled by 0.125*log2e; V^T per head) ; causal
// flash attention v10 (v5 structure + IN-REGISTER P repack via
// cvt_pk+permlane{32,16}_swap — no P LDS bounce; 36.9KB LDS -> 4 blk/CU) ;
// output GEMM -> fp32.

typedef __bf16 bf16x8 __attribute__((ext_vector_type(8)));
typedef __bf16 bf16x4 __attribute__((ext_vector_type(4)));
typedef float f32x4 __attribute__((ext_vector_type(4)));
typedef unsigned int u32x4 __attribute__((ext_vector_type(4)));

#define MFMA __builtin_amdgcn_mfma_f32_16x16x32_bf16

static __device__ __forceinline__ __bf16 f2b(float f) { return (__bf16)f; }

static __device__ __forceinline__ void gload_lds16(const void* g, void* l) {
  __builtin_amdgcn_global_load_lds(
      (const __attribute__((address_space(1))) void*)g,
      (__attribute__((address_space(3))) void*)l, 16, 0, 0);
}

static __device__ __forceinline__ bf16x8 u4_to_b8(u32x4 x) {
  union { u32x4 u; bf16x8 b; } c; c.u = x; return c.b;
}
static __device__ __forceinline__ unsigned cvtpk(float lo, float hi) {
  unsigned r;
  asm("v_cvt_pk_bf16_f32 %0, %1, %2" : "=v"(r) : "v"(lo), "v"(hi));
  return r;
}

#define QSCALE 0.18033688f  /* 0.125 * log2(e) */

// ---------------------------------------------------------------------------
// prep: z<4 -> W_z transpose+convert ; z>=4 -> Q/K/V fp32->bf16 copy.
// grid (1024, 7), block 256.
// ---------------------------------------------------------------------------
__global__ __launch_bounds__(256) void prep_kernel(
    const float* __restrict__ w0, const float* __restrict__ w1,
    const float* __restrict__ w2, const float* __restrict__ w3,
    const float* __restrict__ a0, const float* __restrict__ a1,
    const float* __restrict__ a2, __bf16* __restrict__ outT,
    __bf16* __restrict__ o0, __bf16* __restrict__ o1, __bf16* __restrict__ o2)
{
  const int z = blockIdx.y;
  if (z < 4) {
    const float* W = (z == 0) ? w0 : (z == 1) ? w1 : (z == 2) ? w2 : w3;
    __bf16* O = outT + (size_t)z * 1048576;
    __shared__ float t[32][33];
    const int tx = threadIdx.x & 31, ty = threadIdx.x >> 5;
    const int kb = (blockIdx.x >> 5) * 32, nb = (blockIdx.x & 31) * 32;
#pragma unroll
    for (int i = 0; i < 4; i++)
      t[ty + i * 8][tx] = W[(size_t)(kb + ty + i * 8) * 1024 + nb + tx];
    __syncthreads();
#pragma unroll
    for (int i = 0; i < 4; i++)
      O[(size_t)(nb + ty + i * 8) * 1024 + kb + tx] = f2b(t[tx][ty + i * 8]);
  } else {
    const int j = z - 4;
    const float* src = (j == 0) ? a0 : (j == 1) ? a1 : a2;
    __bf16* dst = (j == 0) ? o0 : (j == 1) ? o1 : o2;
    const size_t c = (size_t)(blockIdx.x * 256 + threadIdx.x) * 16;
#pragma unroll
    for (int it = 0; it < 2; ++it) {
      f32x4 v0 = *(const f32x4*)&src[c + it * 8];
      f32x4 v1 = *(const f32x4*)&src[c + it * 8 + 4];
      bf16x8 w = {f2b(v0[0]), f2b(v0[1]), f2b(v0[2]), f2b(v0[3]),
                  f2b(v1[0]), f2b(v1[1]), f2b(v1[2]), f2b(v1[3])};
      *(bf16x8*)&dst[c + it * 8] = w;
    }
  }
}

// ---------------------------------------------------------------------------
// Standalone weight transpose (fallback path only).
// ---------------------------------------------------------------------------
__global__ __launch_bounds__(256) void wtrans_kernel(
    const float* __restrict__ w0, const float* __restrict__ w1,
    const float* __restrict__ w2, const float* __restrict__ w3,
    __bf16* __restrict__ outT)
{
  const int z = blockIdx.z;
  const float* W = (z == 0) ? w0 : (z == 1) ? w1 : (z == 2) ? w2 : w3;
  __bf16* O = outT + (size_t)z * 1048576;
  __shared__ float t[32][33];
  const int tx = threadIdx.x & 31, ty = threadIdx.x >> 5;
  const int kb = blockIdx.y * 32, nb = blockIdx.x * 32;
#pragma unroll
  for (int i = 0; i < 4; i++)
    t[ty + i * 8][tx] = W[(size_t)(kb + ty + i * 8) * 1024 + nb + tx];
  __syncthreads();
#pragma unroll
  for (int i = 0; i < 4; i++)
    O[(size_t)(nb + ty + i * 8) * 1024 + kb + tx] = f2b(t[tx][ty + i * 8]);
}

// ---------------------------------------------------------------------------
// FAST projection GEMM (m97 structure): C = A(bf16 [4096,1024]) * W^T(bf16).
// z=0: Q head-major, PRE-SCALED by QSCALE. z=1: K head-major. z=2: V^T.
// ---------------------------------------------------------------------------
__global__ __launch_bounds__(256) void gemm_proj_bf16_kernel(
    const __bf16* __restrict__ A0, const __bf16* __restrict__ A1,
    const __bf16* __restrict__ A2, const __bf16* __restrict__ WT,
    __bf16* __restrict__ C0, __bf16* __restrict__ C1, __bf16* __restrict__ C2)
{
  const int z = blockIdx.y;
  const __bf16* A = (z == 0) ? A0 : (z == 1) ? A1 : A2;
  const __bf16* W = WT + (size_t)z * 1048576;
  __bf16* C = (z == 0) ? C0 : (z == 1) ? C1 : C2;
  const float osc = (z == 0) ? QSCALE : 1.0f;

  const int bid = blockIdx.x;
  const int t = (bid & 7) * 32 + (bid >> 3);
  const int mt = t >> 3, nt = t & 7;
  const int mbase = mt * 128, nbase = nt * 128;

  __shared__ __align__(16) __bf16 As[128][32];
  __shared__ __align__(16) __bf16 Bs[128][32];

  const int tid = threadIdx.x;
  const int wid = tid >> 6, lane = tid & 63;
  const int wr = wid >> 1, wc = wid & 1;
  const int lr = lane & 15, kg = lane >> 4;

  f32x4 acc[4][4] = {};

  const int srow = tid >> 2, scol = (tid & 3) * 8;
  const int wbase = tid & 192;

  for (int kb = 0; kb < 32; ++kb) {
    const int k0 = kb * 32;
    __syncthreads();
#pragma unroll
    for (int p = 0; p < 2; ++p) {
      const int r = srow + p * 64;
      gload_lds16(&A[(size_t)(mbase + r) * 1024 + k0 + scol],
                  (__bf16*)As + (size_t)(p * 256 + wbase) * 8);
      gload_lds16(&W[(size_t)(nbase + r) * 1024 + k0 + scol],
                  (__bf16*)Bs + (size_t)(p * 256 + wbase) * 8);
    }
    __syncthreads();

    bf16x8 af[4], bfr[4];
#pragma unroll
    for (int i = 0; i < 4; i++) af[i] = *(const bf16x8*)&As[wr * 64 + i * 16 + lr][kg * 8];
#pragma unroll
    for (int j = 0; j < 4; j++) bfr[j] = *(const bf16x8*)&Bs[wc * 64 + j * 16 + lr][kg * 8];
#pragma unroll
    for (int i = 0; i < 4; i++)
#pragma unroll
      for (int j = 0; j < 4; j++)
        acc[i][j] = MFMA(af[i], bfr[j], acc[i][j], 0, 0, 0);
  }

  if (z == 2) {
#pragma unroll
    for (int i = 0; i < 4; i++)
#pragma unroll
      for (int j = 0; j < 4; j++) {
        const int m0 = mbase + wr * 64 + i * 16 + kg * 4;
        const int n = nbase + wc * 64 + j * 16 + lr;
        const int b = m0 >> 11, s = m0 & 2047, h = n >> 6, dv = n & 63;
        bf16x4 w;
#pragma unroll
        for (int r = 0; r < 4; r++) w[r] = f2b(acc[i][j][r]);
        *(bf16x4*)&C[(((size_t)(b * 16 + h)) * 64 + dv) * 2048 + s] = w;
      }
  } else {
#pragma unroll
    for (int i = 0; i < 4; i++)
#pragma unroll
      for (int j = 0; j < 4; j++)
#pragma unroll
        for (int r = 0; r < 4; r++) {
          const int m = mbase + wr * 64 + i * 16 + kg * 4 + r;
          const int n = nbase + wc * 64 + j * 16 + lr;
          const int b = m >> 11, s = m & 2047, h = n >> 6, dk = n & 63;
          C[(((size_t)(b * 16 + h)) * 2048 + s) * 64 + dk] = f2b(acc[i][j][r] * osc);
        }
  }
}

// ---------------------------------------------------------------------------
// FALLBACK projection GEMM (fp32 A) — used if ws too small.
// ---------------------------------------------------------------------------
__global__ __launch_bounds__(256) void gemm_proj_f32_kernel(
    const float* __restrict__ A0, const float* __restrict__ A1,
    const float* __restrict__ A2, const __bf16* __restrict__ WT,
    __bf16* __restrict__ C0, __bf16* __restrict__ C1, __bf16* __restrict__ C2)
{
  const int z = blockIdx.y;
  const float* A = (z == 0) ? A0 : (z == 1) ? A1 : A2;
  const __bf16* W = WT + (size_t)z * 1048576;
  __bf16* C = (z == 0) ? C0 : (z == 1) ? C1 : C2;
  const float osc = (z == 0) ? QSCALE : 1.0f;

  const int mt = blockIdx.x >> 3, nt = blockIdx.x & 7;
  const int mbase = mt * 128, nbase = nt * 128;

  __shared__ __align__(16) __bf16 As[128][40];
  __shared__ __align__(16) __bf16 Bs[128][40];

  const int tid = threadIdx.x;
  const int wid = tid >> 6, lane = tid & 63;
  const int wr = wid >> 1, wc = wid & 1;
  const int lr = lane & 15, kg = lane >> 4;

  f32x4 acc[4][4] = {};
  const int arow = tid >> 3, ac0 = (tid & 7) * 4;

  for (int kb = 0; kb < 32; ++kb) {
    const int k0 = kb * 32;
#pragma unroll
    for (int p = 0; p < 4; ++p) {
      const int r = arow + p * 32;
      f32x4 av = *(const f32x4*)&A[(size_t)(mbase + r) * 1024 + k0 + ac0];
      bf16x4 cv = {f2b(av[0]), f2b(av[1]), f2b(av[2]), f2b(av[3])};
      *(bf16x4*)&As[r][ac0] = cv;
    }
#pragma unroll
    for (int p = 0; p < 2; ++p) {
      const int idx = p * 256 + tid;
      const int r = idx >> 2, c8 = (idx & 3) * 8;
      *(u32x4*)&Bs[r][c8] = *(const u32x4*)&W[(size_t)(nbase + r) * 1024 + k0 + c8];
    }
    __syncthreads();

    bf16x8 af[4], bfr[4];
#pragma unroll
    for (int i = 0; i < 4; i++) af[i] = *(const bf16x8*)&As[wr * 64 + i * 16 + lr][kg * 8];
#pragma unroll
    for (int j = 0; j < 4; j++) bfr[j] = *(const bf16x8*)&Bs[wc * 64 + j * 16 + lr][kg * 8];
#pragma unroll
    for (int i = 0; i < 4; i++)
#pragma unroll
      for (int j = 0; j < 4; j++)
        acc[i][j] = MFMA(af[i], bfr[j], acc[i][j], 0, 0, 0);
    __syncthreads();
  }

  if (z == 2) {
#pragma unroll
    for (int i = 0; i < 4; i++)
#pragma unroll
      for (int j = 0; j < 4; j++) {
        const int m0 = mbase + wr * 64 + i * 16 + kg * 4;
        const int n = nbase + wc * 64 + j * 16 + lr;
        const int b = m0 >> 11, s = m0 & 2047, h = n >> 6, dv = n & 63;
        bf16x4 w;
#pragma unroll
        for (int r = 0; r < 4; r++) w[r] = f2b(acc[i][j][r]);
        *(bf16x4*)&C[(((size_t)(b * 16 + h)) * 64 + dv) * 2048 + s] = w;
      }
  } else {
#pragma unroll
    for (int i = 0; i < 4; i++)
#pragma unroll
      for (int j = 0; j < 4; j++)
#pragma unroll
        for (int r = 0; r < 4; r++) {
          const int m = mbase + wr * 64 + i * 16 + kg * 4 + r;
          const int n = nbase + wc * 64 + j * 16 + lr;
          const int b = m >> 11, s = m & 2047, h = n >> 6, dk = n & 63;
          C[(((size_t)(b * 16 + h)) * 2048 + s) * 64 + dk] = f2b(acc[i][j][r] * osc);
        }
  }
}

// ---------------------------------------------------------------------------
// Causal flash attention v10 = v5 structure + in-register P repack.
// Q(pre-scaled)/K bf16 [B*H,2048,64]; V^T bf16 [B*H,64,2048].
// grid 1024, block 256 (4 waves x 16 q-rows, QBLK=64). K/V dbuf.
// P repack: lane kg holds kv=16*kvt+4*kg+r after softmax; B-fragment needs
// kv=32*h2+8*kg+e. cvt_pk pairs (r) then permlane32_swap+permlane16_swap
// per register pair places words: [a0,a1,a2,a3]x[b0..b3] ->
// [a0,a2,b0,b2]/[a1,a3,b1,b3]. No Ps LDS -> 36.9KB -> 4 blocks/CU.
// ---------------------------------------------------------------------------
__global__ __launch_bounds__(256) void attn_kernel(
    const __bf16* __restrict__ Qh, const __bf16* __restrict__ Kh,
    const __bf16* __restrict__ VTh, __bf16* __restrict__ AO)
{
  const int lin = blockIdx.x;
  const int l = (lin & 7) * 128 + (lin >> 3);  // XCD-contiguous (1024%8==0)
  const int bh = l >> 5;
  const int qblk = 31 - (l & 31);              // heavy blocks dispatch first
  const int b = bh >> 4, h = bh & 15;
  const __bf16* Qp = Qh + (size_t)bh * 2048 * 64;
  const __bf16* Kp = Kh + (size_t)bh * 2048 * 64;
  const __bf16* Vp = VTh + (size_t)bh * 64 * 2048;

  __shared__ __align__(16) __bf16 Ks[2][64][72];
  __shared__ __align__(16) __bf16 Vt[2][64][72];

  const int tid = threadIdx.x, wid = tid >> 6, lane = tid & 63;
  const int lr = lane & 15, kg = lane >> 4;
  const int sr0 = tid >> 3, sc0 = (tid & 7) * 8;

  const int qbase = qblk << 6;
  const int nkv = qblk + 1;
  const int wq = qbase + wid * 16;

  bf16x8 qf0 = *(const bf16x8*)&Qp[(size_t)(wq + lr) * 64 + kg * 8];
  bf16x8 qf1 = *(const bf16x8*)&Qp[(size_t)(wq + lr) * 64 + 32 + kg * 8];

  f32x4 ot[4] = {};
  float mrow = -1e30f, lsum = 0.f;   // lsum lane-partial

  // stage tile 0
  u32x4 kr0 = *(const u32x4*)&Kp[(size_t)sr0 * 64 + sc0];
  u32x4 kr1 = *(const u32x4*)&Kp[(size_t)(sr0 + 32) * 64 + sc0];
  u32x4 vr0 = *(const u32x4*)&Vp[(size_t)sr0 * 2048 + sc0];
  u32x4 vr1 = *(const u32x4*)&Vp[(size_t)(sr0 + 32) * 2048 + sc0];
  *(u32x4*)&Ks[0][sr0][sc0] = kr0;
  *(u32x4*)&Ks[0][sr0 + 32][sc0] = kr1;
  *(u32x4*)&Vt[0][sr0][sc0] = vr0;
  *(u32x4*)&Vt[0][sr0 + 32][sc0] = vr1;

  int cur = 0;
  for (int t = 0; t < nkv; ++t) {
    const bool pre = (t + 1 < nkv);
    if (pre) {
      const int n0 = (t + 1) << 6;
      kr0 = *(const u32x4*)&Kp[(size_t)(n0 + sr0) * 64 + sc0];
      kr1 = *(const u32x4*)&Kp[(size_t)(n0 + sr0 + 32) * 64 + sc0];
      vr0 = *(const u32x4*)&Vp[(size_t)sr0 * 2048 + n0 + sc0];
      vr1 = *(const u32x4*)&Vp[(size_t)(sr0 + 32) * 2048 + n0 + sc0];
    }
    __syncthreads();

    // ---- S^T = K Q^T ----
    f32x4 st[4] = {};
    __builtin_amdgcn_s_setprio(1);
#pragma unroll
    for (int kvt = 0; kvt < 4; ++kvt) {
      bf16x8 kf0 = *(const bf16x8*)&Ks[cur][kvt * 16 + lr][kg * 8];
      bf16x8 kf1 = *(const bf16x8*)&Ks[cur][kvt * 16 + lr][32 + kg * 8];
      st[kvt] = MFMA(kf0, qf0, st[kvt], 0, 0, 0);
      st[kvt] = MFMA(kf1, qf1, st[kvt], 0, 0, 0);
    }
    __builtin_amdgcn_s_setprio(0);

    // ---- softmax (Q pre-scaled; log2 domain) ----
    float sv[16];
#pragma unroll
    for (int kvt = 0; kvt < 4; ++kvt)
#pragma unroll
      for (int r = 0; r < 4; ++r) sv[kvt * 4 + r] = st[kvt][r];
    if (t == nkv - 1) {  // diagonal tile: causal mask
      const int qidx = wq + lr;
      const int kvb = t << 6;
#pragma unroll
      for (int kvt = 0; kvt < 4; ++kvt)
#pragma unroll
        for (int r = 0; r < 4; ++r)
          if (kvb + kvt * 16 + kg * 4 + r > qidx) sv[kvt * 4 + r] = -1e30f;
    }
    float mx = fmaxf(fmaxf(sv[0], sv[1]), sv[2]);
    mx = fmaxf(fmaxf(mx, sv[3]), sv[4]);
    mx = fmaxf(fmaxf(mx, sv[5]), sv[6]);
    mx = fmaxf(fmaxf(mx, sv[7]), sv[8]);
    mx = fmaxf(fmaxf(mx, sv[9]), sv[10]);
    mx = fmaxf(fmaxf(mx, sv[11]), sv[12]);
    mx = fmaxf(fmaxf(mx, sv[13]), sv[14]);
    mx = fmaxf(mx, sv[15]);
    mx = fmaxf(mx, __shfl_xor(mx, 16));
    mx = fmaxf(mx, __shfl_xor(mx, 32));
    if (__any(mx > mrow + 8.f)) {      // defer-max: rescale only when needed
      const float mnew = fmaxf(mrow, mx);
      const float scl = exp2f(mrow - mnew);
      mrow = mnew;
      lsum *= scl;
#pragma unroll
      for (int dvt = 0; dvt < 4; ++dvt) ot[dvt] *= scl;
    }
    float pexp[16];
#pragma unroll
    for (int i = 0; i < 16; ++i) {
      pexp[i] = exp2f(sv[i] - mrow);
      lsum += pexp[i];
    }

    // ---- P -> B-operand fragments fully in-register ----
    bf16x8 pf[2];
#pragma unroll
    for (int hf = 0; hf < 2; ++hf) {
      unsigned P0 = cvtpk(pexp[8 * hf + 0], pexp[8 * hf + 1]);
      unsigned P1 = cvtpk(pexp[8 * hf + 2], pexp[8 * hf + 3]);
      unsigned P2 = cvtpk(pexp[8 * hf + 4], pexp[8 * hf + 5]);
      unsigned P3 = cvtpk(pexp[8 * hf + 6], pexp[8 * hf + 7]);
      asm("v_permlane32_swap_b32 %0, %1" : "+v"(P0), "+v"(P2));
      asm("v_permlane32_swap_b32 %0, %1" : "+v"(P1), "+v"(P3));
      asm("v_permlane16_swap_b32 %0, %1" : "+v"(P0), "+v"(P2));
      asm("v_permlane16_swap_b32 %0, %1" : "+v"(P1), "+v"(P3));
      u32x4 pv = {P0, P1, P2, P3};
      pf[hf] = u4_to_b8(pv);
    }

    // ---- O^T += V^T P^T ----
#pragma unroll
    for (int h2 = 0; h2 < 2; ++h2) {
      __builtin_amdgcn_s_setprio(1);
#pragma unroll
      for (int dvt = 0; dvt < 4; ++dvt) {
        bf16x8 vf = *(const bf16x8*)&Vt[cur][dvt * 16 + lr][h2 * 32 + kg * 8];
        ot[dvt] = MFMA(vf, pf[h2], ot[dvt], 0, 0, 0);
      }
      __builtin_amdgcn_s_setprio(0);
    }

    if (pre) {
      const int nb = cur ^ 1;
      *(u32x4*)&Ks[nb][sr0][sc0] = kr0;
      *(u32x4*)&Ks[nb][sr0 + 32][sc0] = kr1;
      *(u32x4*)&Vt[nb][sr0][sc0] = vr0;
      *(u32x4*)&Vt[nb][sr0 + 32][sc0] = vr1;
    }
    cur ^= 1;
  }

  // epilogue: combine lane-partial lsum across the row's 4 lanes, then store
  lsum += __shfl_xor(lsum, 16);
  lsum += __shfl_xor(lsum, 32);
  const float rl = 1.f / lsum;
  const int q = wq + lr;
#pragma unroll
  for (int dvt = 0; dvt < 4; ++dvt) {
    bf16x4 w;
#pragma unroll
    for (int r = 0; r < 4; ++r) w[r] = f2b(ot[dvt][r] * rl);
    *(bf16x4*)&AO[((size_t)(b * 2048 + q)) * 1024 + h * 64 + dvt * 16 + kg * 4] = w;
  }
}

// ---------------------------------------------------------------------------
// Output GEMM (m97 structure): out(fp32) = AO(bf16) * Wo^T(bf16).
// ---------------------------------------------------------------------------
__global__ __launch_bounds__(256) void gemm_out_kernel(
    const __bf16* __restrict__ A, const __bf16* __restrict__ WT,
    float* __restrict__ Out)
{
  const int bid = blockIdx.x;
  const int t = (bid & 7) * 32 + (bid >> 3);
  const int mt = t >> 3, nt = t & 7;
  const int mbase = mt * 128, nbase = nt * 128;

  __shared__ __align__(16) __bf16 As[128][32];
  __shared__ __align__(16) __bf16 Bs[128][32];

  const int tid = threadIdx.x;
  const int wid = tid >> 6, lane = tid & 63;
  const int wr = wid >> 1, wc = wid & 1;
  const int lr = lane & 15, kg = lane >> 4;

  f32x4 acc[4][4] = {};

  const int srow = tid >> 2, scol = (tid & 3) * 8;
  const int wbase = tid & 192;

  for (int kb = 0; kb < 32; ++kb) {
    const int k0 = kb * 32;
    __syncthreads();
#pragma unroll
    for (int p = 0; p < 2; ++p) {
      const int r = srow + p * 64;
      gload_lds16(&A[(size_t)(mbase + r) * 1024 + k0 + scol],
                  (__bf16*)As + (size_t)(p * 256 + wbase) * 8);
      gload_lds16(&WT[(size_t)(nbase + r) * 1024 + k0 + scol],
                  (__bf16*)Bs + (size_t)(p * 256 + wbase) * 8);
    }
    __syncthreads();

    bf16x8 af[4], bfr[4];
#pragma unroll
    for (int i = 0; i < 4; i++) af[i] = *(const bf16x8*)&As[wr * 64 + i * 16 + lr][kg * 8];
#pragma unroll
    for (int j = 0; j < 4; j++) bfr[j] = *(const bf16x8*)&Bs[wc * 64 + j * 16 + lr][kg * 8];
#pragma unroll
    for (int i = 0; i < 4; i++)
#pragma unroll
      for (int j = 0; j < 4; j++)
        acc[i][j] = MFMA(af[i], bfr[j], acc[i][j], 0, 0, 0);
  }

#pragma unroll
  for (int i = 0; i < 4; i++)
#pragma unroll
    for (int j = 0; j < 4; j++)
#pragma unroll
      for (int r = 0; r < 4; r++) {
        const int m = mbase + wr * 64 + i * 16 + kg * 4 + r;
        const int n = nbase + wc * 64 + j * 16 + lr;
        Out[(size_t)m * 1024 + n] = acc[i][j][r];
      }
}

// ---------------------------------------------------------------------------
extern "C" void kernel_launch(void* const* d_in, const int* in_sizes, int n_in,
                              void* d_out, int out_size, void* d_ws, size_t ws_size,
                              hipStream_t stream) {
  const float* Q  = (const float*)d_in[0];
  const float* K  = (const float*)d_in[1];
  const float* V  = (const float*)d_in[2];
  const float* Wq = (const float*)d_in[3];
  const float* Wk = (const float*)d_in[4];
  const float* Wv = (const float*)d_in[5];
  const float* Wo = (const float*)d_in[6];
  float* out = (float*)d_out;

  const size_t M4 = 4194304;
  __bf16* wT  = (__bf16*)d_ws;
  __bf16* qb  = wT + M4;
  __bf16* kb  = qb + M4;
  __bf16* vtb = kb + M4;

  const bool fast = ws_size >= (size_t)(28 * 1048576) * 2;  // 56 MiB

  __bf16* ao;
  if (fast) {
    __bf16* qa = vtb + M4;
    __bf16* ka = qa + M4;
    __bf16* va = ka + M4;
    ao = qa;
    prep_kernel<<<dim3(1024, 7), 256, 0, stream>>>(Wq, Wk, Wv, Wo, Q, K, V,
                                                   wT, qa, ka, va);
    gemm_proj_bf16_kernel<<<dim3(256, 3), 256, 0, stream>>>(qa, ka, va, wT,
                                                            qb, kb, vtb);
  } else {
    ao = vtb + M4;
    wtrans_kernel<<<dim3(32, 32, 4), 256, 0, stream>>>(Wq, Wk, Wv, Wo, wT);
    gemm_proj_f32_kernel<<<dim3(256, 3), 256, 0, stream>>>(Q, K, V, wT,
                                                           qb, kb, vtb);
  }

  attn_kernel<<<dim3(1024), 256, 0, stream>>>(qb, kb, vtb, ao);
  gemm_out_kernel<<<dim3(256), 256, 0, stream>>>(ao, wT + 3 * 1048576, out);
}

// Round 14
// 136.057 us; speedup vs baseline: 1.0883x; 1.0883x over previous
//
#include <hip/hip_runtime.h>
#include <cstdint>
#include <cstddef>

// MHA: B=2, S=2048, D=1024, H=16, DK=DV=64, causal.
// Pipeline: prep (W->bf16 W^T  +  Q/K/V fp32->bf16, one kernel) ;
// projection GEMMs (global_load_lds; Q pre-scaled by 0.125*log2e; V^T per
// head) ; causal flash attention v5 (4 waves x 16 q-rows, LDS P-bounce,
// defer-max, dbuf, 1 barrier/iter — verified 65 us) ; output GEMM -> fp32.
// [Round 14: byte-identical revert to the round-12 best, 136.2 us.]

typedef __bf16 bf16x8 __attribute__((ext_vector_type(8)));
typedef __bf16 bf16x4 __attribute__((ext_vector_type(4)));
typedef float f32x4 __attribute__((ext_vector_type(4)));
typedef unsigned int u32x4 __attribute__((ext_vector_type(4)));

#define MFMA __builtin_amdgcn_mfma_f32_16x16x32_bf16

static __device__ __forceinline__ __bf16 f2b(float f) { return (__bf16)f; }

static __device__ __forceinline__ void gload_lds16(const void* g, void* l) {
  __builtin_amdgcn_global_load_lds(
      (const __attribute__((address_space(1))) void*)g,
      (__attribute__((address_space(3))) void*)l, 16, 0, 0);
}

#define QSCALE 0.18033688f  /* 0.125 * log2(e) */

// ---------------------------------------------------------------------------
// prep: z<4  -> W_z transpose+convert: O[n][k] = (bf16) W_z[k][n]
//       z>=4 -> Q/K/V fp32->bf16 flat copy
// grid (1024, 7), block 256.
// ---------------------------------------------------------------------------
__global__ __launch_bounds__(256) void prep_kernel(
    const float* __restrict__ w0, const float* __restrict__ w1,
    const float* __restrict__ w2, const float* __restrict__ w3,
    const float* __restrict__ a0, const float* __restrict__ a1,
    const float* __restrict__ a2, __bf16* __restrict__ outT,
    __bf16* __restrict__ o0, __bf16* __restrict__ o1, __bf16* __restrict__ o2)
{
  const int z = blockIdx.y;
  if (z < 4) {
    const float* W = (z == 0) ? w0 : (z == 1) ? w1 : (z == 2) ? w2 : w3;
    __bf16* O = outT + (size_t)z * 1048576;
    __shared__ float t[32][33];
    const int tx = threadIdx.x & 31, ty = threadIdx.x >> 5;
    const int kb = (blockIdx.x >> 5) * 32, nb = (blockIdx.x & 31) * 32;
#pragma unroll
    for (int i = 0; i < 4; i++)
      t[ty + i * 8][tx] = W[(size_t)(kb + ty + i * 8) * 1024 + nb + tx];
    __syncthreads();
#pragma unroll
    for (int i = 0; i < 4; i++)
      O[(size_t)(nb + ty + i * 8) * 1024 + kb + tx] = f2b(t[tx][ty + i * 8]);
  } else {
    const int j = z - 4;
    const float* src = (j == 0) ? a0 : (j == 1) ? a1 : a2;
    __bf16* dst = (j == 0) ? o0 : (j == 1) ? o1 : o2;
    const size_t c = (size_t)(blockIdx.x * 256 + threadIdx.x) * 16;
#pragma unroll
    for (int it = 0; it < 2; ++it) {
      f32x4 v0 = *(const f32x4*)&src[c + it * 8];
      f32x4 v1 = *(const f32x4*)&src[c + it * 8 + 4];
      bf16x8 w = {f2b(v0[0]), f2b(v0[1]), f2b(v0[2]), f2b(v0[3]),
                  f2b(v1[0]), f2b(v1[1]), f2b(v1[2]), f2b(v1[3])};
      *(bf16x8*)&dst[c + it * 8] = w;
    }
  }
}

// ---------------------------------------------------------------------------
// Standalone weight transpose (fallback path only).
// ---------------------------------------------------------------------------
__global__ __launch_bounds__(256) void wtrans_kernel(
    const float* __restrict__ w0, const float* __restrict__ w1,
    const float* __restrict__ w2, const float* __restrict__ w3,
    __bf16* __restrict__ outT)
{
  const int z = blockIdx.z;
  const float* W = (z == 0) ? w0 : (z == 1) ? w1 : (z == 2) ? w2 : w3;
  __bf16* O = outT + (size_t)z * 1048576;
  __shared__ float t[32][33];
  const int tx = threadIdx.x & 31, ty = threadIdx.x >> 5;
  const int kb = blockIdx.y * 32, nb = blockIdx.x * 32;
#pragma unroll
  for (int i = 0; i < 4; i++)
    t[ty + i * 8][tx] = W[(size_t)(kb + ty + i * 8) * 1024 + nb + tx];
  __syncthreads();
#pragma unroll
  for (int i = 0; i < 4; i++)
    O[(size_t)(nb + ty + i * 8) * 1024 + kb + tx] = f2b(t[tx][ty + i * 8]);
}

// ---------------------------------------------------------------------------
// FAST projection GEMM (m97 structure): C = A(bf16 [4096,1024]) * W^T(bf16).
// z=0: Q head-major, PRE-SCALED by QSCALE. z=1: K head-major. z=2: V^T.
// ---------------------------------------------------------------------------
__global__ __launch_bounds__(256) void gemm_proj_bf16_kernel(
    const __bf16* __restrict__ A0, const __bf16* __restrict__ A1,
    const __bf16* __restrict__ A2, const __bf16* __restrict__ WT,
    __bf16* __restrict__ C0, __bf16* __restrict__ C1, __bf16* __restrict__ C2)
{
  const int z = blockIdx.y;
  const __bf16* A = (z == 0) ? A0 : (z == 1) ? A1 : A2;
  const __bf16* W = WT + (size_t)z * 1048576;
  __bf16* C = (z == 0) ? C0 : (z == 1) ? C1 : C2;
  const float osc = (z == 0) ? QSCALE : 1.0f;

  const int bid = blockIdx.x;
  const int t = (bid & 7) * 32 + (bid >> 3);
  const int mt = t >> 3, nt = t & 7;
  const int mbase = mt * 128, nbase = nt * 128;

  __shared__ __align__(16) __bf16 As[128][32];
  __shared__ __align__(16) __bf16 Bs[128][32];

  const int tid = threadIdx.x;
  const int wid = tid >> 6, lane = tid & 63;
  const int wr = wid >> 1, wc = wid & 1;
  const int lr = lane & 15, kg = lane >> 4;

  f32x4 acc[4][4] = {};

  const int srow = tid >> 2, scol = (tid & 3) * 8;
  const int wbase = tid & 192;

  for (int kb = 0; kb < 32; ++kb) {
    const int k0 = kb * 32;
    __syncthreads();
#pragma unroll
    for (int p = 0; p < 2; ++p) {
      const int r = srow + p * 64;
      gload_lds16(&A[(size_t)(mbase + r) * 1024 + k0 + scol],
                  (__bf16*)As + (size_t)(p * 256 + wbase) * 8);
      gload_lds16(&W[(size_t)(nbase + r) * 1024 + k0 + scol],
                  (__bf16*)Bs + (size_t)(p * 256 + wbase) * 8);
    }
    __syncthreads();

    bf16x8 af[4], bfr[4];
#pragma unroll
    for (int i = 0; i < 4; i++) af[i] = *(const bf16x8*)&As[wr * 64 + i * 16 + lr][kg * 8];
#pragma unroll
    for (int j = 0; j < 4; j++) bfr[j] = *(const bf16x8*)&Bs[wc * 64 + j * 16 + lr][kg * 8];
#pragma unroll
    for (int i = 0; i < 4; i++)
#pragma unroll
      for (int j = 0; j < 4; j++)
        acc[i][j] = MFMA(af[i], bfr[j], acc[i][j], 0, 0, 0);
  }

  if (z == 2) {
#pragma unroll
    for (int i = 0; i < 4; i++)
#pragma unroll
      for (int j = 0; j < 4; j++) {
        const int m0 = mbase + wr * 64 + i * 16 + kg * 4;
        const int n = nbase + wc * 64 + j * 16 + lr;
        const int b = m0 >> 11, s = m0 & 2047, h = n >> 6, dv = n & 63;
        bf16x4 w;
#pragma unroll
        for (int r = 0; r < 4; r++) w[r] = f2b(acc[i][j][r]);
        *(bf16x4*)&C[(((size_t)(b * 16 + h)) * 64 + dv) * 2048 + s] = w;
      }
  } else {
#pragma unroll
    for (int i = 0; i < 4; i++)
#pragma unroll
      for (int j = 0; j < 4; j++)
#pragma unroll
        for (int r = 0; r < 4; r++) {
          const int m = mbase + wr * 64 + i * 16 + kg * 4 + r;
          const int n = nbase + wc * 64 + j * 16 + lr;
          const int b = m >> 11, s = m & 2047, h = n >> 6, dk = n & 63;
          C[(((size_t)(b * 16 + h)) * 2048 + s) * 64 + dk] = f2b(acc[i][j][r] * osc);
        }
  }
}

// ---------------------------------------------------------------------------
// FALLBACK projection GEMM (fp32 A) — used if ws too small.
// ---------------------------------------------------------------------------
__global__ __launch_bounds__(256) void gemm_proj_f32_kernel(
    const float* __restrict__ A0, const float* __restrict__ A1,
    const float* __restrict__ A2, const __bf16* __restrict__ WT,
    __bf16* __restrict__ C0, __bf16* __restrict__ C1, __bf16* __restrict__ C2)
{
  const int z = blockIdx.y;
  const float* A = (z == 0) ? A0 : (z == 1) ? A1 : A2;
  const __bf16* W = WT + (size_t)z * 1048576;
  __bf16* C = (z == 0) ? C0 : (z == 1) ? C1 : C2;
  const float osc = (z == 0) ? QSCALE : 1.0f;

  const int mt = blockIdx.x >> 3, nt = blockIdx.x & 7;
  const int mbase = mt * 128, nbase = nt * 128;

  __shared__ __align__(16) __bf16 As[128][40];
  __shared__ __align__(16) __bf16 Bs[128][40];

  const int tid = threadIdx.x;
  const int wid = tid >> 6, lane = tid & 63;
  const int wr = wid >> 1, wc = wid & 1;
  const int lr = lane & 15, kg = lane >> 4;

  f32x4 acc[4][4] = {};
  const int arow = tid >> 3, ac0 = (tid & 7) * 4;

  for (int kb = 0; kb < 32; ++kb) {
    const int k0 = kb * 32;
#pragma unroll
    for (int p = 0; p < 4; ++p) {
      const int r = arow + p * 32;
      f32x4 av = *(const f32x4*)&A[(size_t)(mbase + r) * 1024 + k0 + ac0];
      bf16x4 cv = {f2b(av[0]), f2b(av[1]), f2b(av[2]), f2b(av[3])};
      *(bf16x4*)&As[r][ac0] = cv;
    }
#pragma unroll
    for (int p = 0; p < 2; ++p) {
      const int idx = p * 256 + tid;
      const int r = idx >> 2, c8 = (idx & 3) * 8;
      *(u32x4*)&Bs[r][c8] = *(const u32x4*)&W[(size_t)(nbase + r) * 1024 + k0 + c8];
    }
    __syncthreads();

    bf16x8 af[4], bfr[4];
#pragma unroll
    for (int i = 0; i < 4; i++) af[i] = *(const bf16x8*)&As[wr * 64 + i * 16 + lr][kg * 8];
#pragma unroll
    for (int j = 0; j < 4; j++) bfr[j] = *(const bf16x8*)&Bs[wc * 64 + j * 16 + lr][kg * 8];
#pragma unroll
    for (int i = 0; i < 4; i++)
#pragma unroll
      for (int j = 0; j < 4; j++)
        acc[i][j] = MFMA(af[i], bfr[j], acc[i][j], 0, 0, 0);
    __syncthreads();
  }

  if (z == 2) {
#pragma unroll
    for (int i = 0; i < 4; i++)
#pragma unroll
      for (int j = 0; j < 4; j++) {
        const int m0 = mbase + wr * 64 + i * 16 + kg * 4;
        const int n = nbase + wc * 64 + j * 16 + lr;
        const int b = m0 >> 11, s = m0 & 2047, h = n >> 6, dv = n & 63;
        bf16x4 w;
#pragma unroll
        for (int r = 0; r < 4; r++) w[r] = f2b(acc[i][j][r]);
        *(bf16x4*)&C[(((size_t)(b * 16 + h)) * 64 + dv) * 2048 + s] = w;
      }
  } else {
#pragma unroll
    for (int i = 0; i < 4; i++)
#pragma unroll
      for (int j = 0; j < 4; j++)
#pragma unroll
        for (int r = 0; r < 4; r++) {
          const int m = mbase + wr * 64 + i * 16 + kg * 4 + r;
          const int n = nbase + wc * 64 + j * 16 + lr;
          const int b = m >> 11, s = m & 2047, h = n >> 6, dk = n & 63;
          C[(((size_t)(b * 16 + h)) * 2048 + s) * 64 + dk] = f2b(acc[i][j][r] * osc);
        }
  }
}

// ---------------------------------------------------------------------------
// Causal flash attention v5 (verified 65.0 us).
// Q(pre-scaled)/K bf16 [B*H,2048,64]; V^T bf16 [B*H,64,2048].
// grid 1024: one 64-row q-block per block, qblk-descending within
// XCD-contiguous chunks (4 heads/XCD). block 256 (4 waves, 16 q-rows each).
// S^T = K Q^T; lane-local softmax + defer-max(THR=8); lane-partial lsum;
// P via per-wave LDS bounce; PV = plain b128 V^T fragments. K/V dbuf.
// ---------------------------------------------------------------------------
__global__ __launch_bounds__(256) void attn_kernel(
    const __bf16* __restrict__ Qh, const __bf16* __restrict__ Kh,
    const __bf16* __restrict__ VTh, __bf16* __restrict__ AO)
{
  const int lin = blockIdx.x;
  const int l = (lin & 7) * 128 + (lin >> 3);  // XCD-contiguous (1024%8==0)
  const int bh = l >> 5;
  const int qblk = 31 - (l & 31);              // heavy blocks dispatch first
  const int b = bh >> 4, h = bh & 15;
  const __bf16* Qp = Qh + (size_t)bh * 2048 * 64;
  const __bf16* Kp = Kh + (size_t)bh * 2048 * 64;
  const __bf16* Vp = VTh + (size_t)bh * 64 * 2048;

  __shared__ __align__(16) __bf16 Ks[2][64][72];
  __shared__ __align__(16) __bf16 Vt[2][64][72];
  __shared__ __align__(16) __bf16 Ps[4][16][72];

  const int tid = threadIdx.x, wid = tid >> 6, lane = tid & 63;
  const int lr = lane & 15, kg = lane >> 4;
  const int sr0 = tid >> 3, sc0 = (tid & 7) * 8;

  const int qbase = qblk << 6;
  const int nkv = qblk + 1;
  const int wq = qbase + wid * 16;

  bf16x8 qf0 = *(const bf16x8*)&Qp[(size_t)(wq + lr) * 64 + kg * 8];
  bf16x8 qf1 = *(const bf16x8*)&Qp[(size_t)(wq + lr) * 64 + 32 + kg * 8];

  f32x4 ot[4] = {};
  float mrow = -1e30f, lsum = 0.f;   // lsum lane-partial

  // stage tile 0
  u32x4 kr0 = *(const u32x4*)&Kp[(size_t)sr0 * 64 + sc0];
  u32x4 kr1 = *(const u32x4*)&Kp[(size_t)(sr0 + 32) * 64 + sc0];
  u32x4 vr0 = *(const u32x4*)&Vp[(size_t)sr0 * 2048 + sc0];
  u32x4 vr1 = *(const u32x4*)&Vp[(size_t)(sr0 + 32) * 2048 + sc0];
  *(u32x4*)&Ks[0][sr0][sc0] = kr0;
  *(u32x4*)&Ks[0][sr0 + 32][sc0] = kr1;
  *(u32x4*)&Vt[0][sr0][sc0] = vr0;
  *(u32x4*)&Vt[0][sr0 + 32][sc0] = vr1;

  int cur = 0;
  for (int t = 0; t < nkv; ++t) {
    const bool pre = (t + 1 < nkv);
    if (pre) {
      const int n0 = (t + 1) << 6;
      kr0 = *(const u32x4*)&Kp[(size_t)(n0 + sr0) * 64 + sc0];
      kr1 = *(const u32x4*)&Kp[(size_t)(n0 + sr0 + 32) * 64 + sc0];
      vr0 = *(const u32x4*)&Vp[(size_t)sr0 * 2048 + n0 + sc0];
      vr1 = *(const u32x4*)&Vp[(size_t)(sr0 + 32) * 2048 + n0 + sc0];
    }
    __syncthreads();

    // ---- S^T = K Q^T ----
    f32x4 st[4] = {};
    __builtin_amdgcn_s_setprio(1);
#pragma unroll
    for (int kvt = 0; kvt < 4; ++kvt) {
      bf16x8 kf0 = *(const bf16x8*)&Ks[cur][kvt * 16 + lr][kg * 8];
      bf16x8 kf1 = *(const bf16x8*)&Ks[cur][kvt * 16 + lr][32 + kg * 8];
      st[kvt] = MFMA(kf0, qf0, st[kvt], 0, 0, 0);
      st[kvt] = MFMA(kf1, qf1, st[kvt], 0, 0, 0);
    }
    __builtin_amdgcn_s_setprio(0);

    // ---- softmax (Q pre-scaled; log2 domain) ----
    float sv[16];
#pragma unroll
    for (int kvt = 0; kvt < 4; ++kvt)
#pragma unroll
      for (int r = 0; r < 4; ++r) sv[kvt * 4 + r] = st[kvt][r];
    if (t == nkv - 1) {  // diagonal tile: causal mask
      const int qidx = wq + lr;
      const int kvb = t << 6;
#pragma unroll
      for (int kvt = 0; kvt < 4; ++kvt)
#pragma unroll
        for (int r = 0; r < 4; ++r)
          if (kvb + kvt * 16 + kg * 4 + r > qidx) sv[kvt * 4 + r] = -1e30f;
    }
    float mx = fmaxf(fmaxf(sv[0], sv[1]), sv[2]);
    mx = fmaxf(fmaxf(mx, sv[3]), sv[4]);
    mx = fmaxf(fmaxf(mx, sv[5]), sv[6]);
    mx = fmaxf(fmaxf(mx, sv[7]), sv[8]);
    mx = fmaxf(fmaxf(mx, sv[9]), sv[10]);
    mx = fmaxf(fmaxf(mx, sv[11]), sv[12]);
    mx = fmaxf(fmaxf(mx, sv[13]), sv[14]);
    mx = fmaxf(mx, sv[15]);
    mx = fmaxf(mx, __shfl_xor(mx, 16));
    mx = fmaxf(mx, __shfl_xor(mx, 32));
    if (__any(mx > mrow + 8.f)) {      // defer-max: rescale only when needed
      const float mnew = fmaxf(mrow, mx);
      const float scl = exp2f(mrow - mnew);
      mrow = mnew;
      lsum *= scl;
#pragma unroll
      for (int dvt = 0; dvt < 4; ++dvt) ot[dvt] *= scl;
    }
#pragma unroll
    for (int kvt = 0; kvt < 4; ++kvt) {
      bf16x4 pk;
#pragma unroll
      for (int r = 0; r < 4; ++r) {
        const float p = exp2f(sv[kvt * 4 + r] - mrow);
        lsum += p;
        pk[r] = f2b(p);
      }
      *(bf16x4*)&Ps[wid][lr][kvt * 16 + kg * 4] = pk;
    }

    // ---- O^T += V^T P^T ----
#pragma unroll
    for (int h2 = 0; h2 < 2; ++h2) {
      bf16x8 pf = *(const bf16x8*)&Ps[wid][lr][h2 * 32 + kg * 8];
      __builtin_amdgcn_s_setprio(1);
#pragma unroll
      for (int dvt = 0; dvt < 4; ++dvt) {
        bf16x8 vf = *(const bf16x8*)&Vt[cur][dvt * 16 + lr][h2 * 32 + kg * 8];
        ot[dvt] = MFMA(vf, pf, ot[dvt], 0, 0, 0);
      }
      __builtin_amdgcn_s_setprio(0);
    }

    if (pre) {
      const int nb = cur ^ 1;
      *(u32x4*)&Ks[nb][sr0][sc0] = kr0;
      *(u32x4*)&Ks[nb][sr0 + 32][sc0] = kr1;
      *(u32x4*)&Vt[nb][sr0][sc0] = vr0;
      *(u32x4*)&Vt[nb][sr0 + 32][sc0] = vr1;
    }
    cur ^= 1;
  }

  // epilogue: combine lane-partial lsum across the row's 4 lanes, then store
  lsum += __shfl_xor(lsum, 16);
  lsum += __shfl_xor(lsum, 32);
  const float rl = 1.f / lsum;
  const int q = wq + lr;
#pragma unroll
  for (int dvt = 0; dvt < 4; ++dvt) {
    bf16x4 w;
#pragma unroll
    for (int r = 0; r < 4; ++r) w[r] = f2b(ot[dvt][r] * rl);
    *(bf16x4*)&AO[((size_t)(b * 2048 + q)) * 1024 + h * 64 + dvt * 16 + kg * 4] = w;
  }
}

// ---------------------------------------------------------------------------
// Output GEMM (m97 structure): out(fp32) = AO(bf16) * Wo^T(bf16).
// ---------------------------------------------------------------------------
__global__ __launch_bounds__(256) void gemm_out_kernel(
    const __bf16* __restrict__ A, const __bf16* __restrict__ WT,
    float* __restrict__ Out)
{
  const int bid = blockIdx.x;
  const int t = (bid & 7) * 32 + (bid >> 3);
  const int mt = t >> 3, nt = t & 7;
  const int mbase = mt * 128, nbase = nt * 128;

  __shared__ __align__(16) __bf16 As[128][32];
  __shared__ __align__(16) __bf16 Bs[128][32];

  const int tid = threadIdx.x;
  const int wid = tid >> 6, lane = tid & 63;
  const int wr = wid >> 1, wc = wid & 1;
  const int lr = lane & 15, kg = lane >> 4;

  f32x4 acc[4][4] = {};

  const int srow = tid >> 2, scol = (tid & 3) * 8;
  const int wbase = tid & 192;

  for (int kb = 0; kb < 32; ++kb) {
    const int k0 = kb * 32;
    __syncthreads();
#pragma unroll
    for (int p = 0; p < 2; ++p) {
      const int r = srow + p * 64;
      gload_lds16(&A[(size_t)(mbase + r) * 1024 + k0 + scol],
                  (__bf16*)As + (size_t)(p * 256 + wbase) * 8);
      gload_lds16(&WT[(size_t)(nbase + r) * 1024 + k0 + scol],
                  (__bf16*)Bs + (size_t)(p * 256 + wbase) * 8);
    }
    __syncthreads();

    bf16x8 af[4], bfr[4];
#pragma unroll
    for (int i = 0; i < 4; i++) af[i] = *(const bf16x8*)&As[wr * 64 + i * 16 + lr][kg * 8];
#pragma unroll
    for (int j = 0; j < 4; j++) bfr[j] = *(const bf16x8*)&Bs[wc * 64 + j * 16 + lr][kg * 8];
#pragma unroll
    for (int i = 0; i < 4; i++)
#pragma unroll
      for (int j = 0; j < 4; j++)
        acc[i][j] = MFMA(af[i], bfr[j], acc[i][j], 0, 0, 0);
  }

#pragma unroll
  for (int i = 0; i < 4; i++)
#pragma unroll
    for (int j = 0; j < 4; j++)
#pragma unroll
      for (int r = 0; r < 4; r++) {
        const int m = mbase + wr * 64 + i * 16 + kg * 4 + r;
        const int n = nbase + wc * 64 + j * 16 + lr;
        Out[(size_t)m * 1024 + n] = acc[i][j][r];
      }
}

// ---------------------------------------------------------------------------
extern "C" void kernel_launch(void* const* d_in, const int* in_sizes, int n_in,
                              void* d_out, int out_size, void* d_ws, size_t ws_size,
                              hipStream_t stream) {
  const float* Q  = (const float*)d_in[0];
  const float* K  = (const float*)d_in[1];
  const float* V  = (const float*)d_in[2];
  const float* Wq = (const float*)d_in[3];
  const float* Wk = (const float*)d_in[4];
  const float* Wv = (const float*)d_in[5];
  const float* Wo = (const float*)d_in[6];
  float* out = (float*)d_out;

  const size_t M4 = 4194304;
  __bf16* wT  = (__bf16*)d_ws;
  __bf16* qb  = wT + M4;
  __bf16* kb  = qb + M4;
  __bf16* vtb = kb + M4;

  const bool fast = ws_size >= (size_t)(28 * 1048576) * 2;  // 56 MiB

  __bf16* ao;
  if (fast) {
    __bf16* qa = vtb + M4;
    __bf16* ka = qa + M4;
    __bf16* va = ka + M4;
    ao = qa;
    prep_kernel<<<dim3(1024, 7), 256, 0, stream>>>(Wq, Wk, Wv, Wo, Q, K, V,
                                                   wT, qa, ka, va);
    gemm_proj_bf16_kernel<<<dim3(256, 3), 256, 0, stream>>>(qa, ka, va, wT,
                                                            qb, kb, vtb);
  } else {
    ao = vtb + M4;
    wtrans_kernel<<<dim3(32, 32, 4), 256, 0, stream>>>(Wq, Wk, Wv, Wo, wT);
    gemm_proj_f32_kernel<<<dim3(256, 3), 256, 0, stream>>>(Q, K, V, wT,
                                                           qb, kb, vtb);
  }

  attn_kernel<<<dim3(1024), 256, 0, stream>>>(qb, kb, vtb, ao);
  gemm_out_kernel<<<dim3(256), 256, 0, stream>>>(ao, wT + 3 * 1048576, out);
}

// Round 15
// 133.501 us; speedup vs baseline: 1.1092x; 1.0191x over previous
//
#include <hip/hip_runtime.h>
#include <cstdint>
#include <cstddef>

// MHA: B=2, S=2048, D=1024, H=16, DK=DV=64, causal.
// Pipeline: prep (W->bf16 W^T  +  Q/K/V fp32->bf16, one kernel) ;
// projection GEMMs (global_load_lds; Q pre-scaled by 0.125*log2e; V^T per
// head) ; causal flash attention v5.1 (4 waves x 16 q-rows, LDS P-bounce,
// defer-max with BRANCH-DEFERRED row-max shfls, dbuf, 1 barrier/iter) ;
// output GEMM -> fp32.

typedef __bf16 bf16x8 __attribute__((ext_vector_type(8)));
typedef __bf16 bf16x4 __attribute__((ext_vector_type(4)));
typedef float f32x4 __attribute__((ext_vector_type(4)));
typedef unsigned int u32x4 __attribute__((ext_vector_type(4)));

#define MFMA __builtin_amdgcn_mfma_f32_16x16x32_bf16

static __device__ __forceinline__ __bf16 f2b(float f) { return (__bf16)f; }

static __device__ __forceinline__ void gload_lds16(const void* g, void* l) {
  __builtin_amdgcn_global_load_lds(
      (const __attribute__((address_space(1))) void*)g,
      (__attribute__((address_space(3))) void*)l, 16, 0, 0);
}

#define QSCALE 0.18033688f  /* 0.125 * log2(e) */

// ---------------------------------------------------------------------------
// prep: z<4  -> W_z transpose+convert: O[n][k] = (bf16) W_z[k][n]
//       z>=4 -> Q/K/V fp32->bf16 flat copy
// grid (1024, 7), block 256.
// ---------------------------------------------------------------------------
__global__ __launch_bounds__(256) void prep_kernel(
    const float* __restrict__ w0, const float* __restrict__ w1,
    const float* __restrict__ w2, const float* __restrict__ w3,
    const float* __restrict__ a0, const float* __restrict__ a1,
    const float* __restrict__ a2, __bf16* __restrict__ outT,
    __bf16* __restrict__ o0, __bf16* __restrict__ o1, __bf16* __restrict__ o2)
{
  const int z = blockIdx.y;
  if (z < 4) {
    const float* W = (z == 0) ? w0 : (z == 1) ? w1 : (z == 2) ? w2 : w3;
    __bf16* O = outT + (size_t)z * 1048576;
    __shared__ float t[32][33];
    const int tx = threadIdx.x & 31, ty = threadIdx.x >> 5;
    const int kb = (blockIdx.x >> 5) * 32, nb = (blockIdx.x & 31) * 32;
#pragma unroll
    for (int i = 0; i < 4; i++)
      t[ty + i * 8][tx] = W[(size_t)(kb + ty + i * 8) * 1024 + nb + tx];
    __syncthreads();
#pragma unroll
    for (int i = 0; i < 4; i++)
      O[(size_t)(nb + ty + i * 8) * 1024 + kb + tx] = f2b(t[tx][ty + i * 8]);
  } else {
    const int j = z - 4;
    const float* src = (j == 0) ? a0 : (j == 1) ? a1 : a2;
    __bf16* dst = (j == 0) ? o0 : (j == 1) ? o1 : o2;
    const size_t c = (size_t)(blockIdx.x * 256 + threadIdx.x) * 16;
#pragma unroll
    for (int it = 0; it < 2; ++it) {
      f32x4 v0 = *(const f32x4*)&src[c + it * 8];
      f32x4 v1 = *(const f32x4*)&src[c + it * 8 + 4];
      bf16x8 w = {f2b(v0[0]), f2b(v0[1]), f2b(v0[2]), f2b(v0[3]),
                  f2b(v1[0]), f2b(v1[1]), f2b(v1[2]), f2b(v1[3])};
      *(bf16x8*)&dst[c + it * 8] = w;
    }
  }
}

// ---------------------------------------------------------------------------
// Standalone weight transpose (fallback path only).
// ---------------------------------------------------------------------------
__global__ __launch_bounds__(256) void wtrans_kernel(
    const float* __restrict__ w0, const float* __restrict__ w1,
    const float* __restrict__ w2, const float* __restrict__ w3,
    __bf16* __restrict__ outT)
{
  const int z = blockIdx.z;
  const float* W = (z == 0) ? w0 : (z == 1) ? w1 : (z == 2) ? w2 : w3;
  __bf16* O = outT + (size_t)z * 1048576;
  __shared__ float t[32][33];
  const int tx = threadIdx.x & 31, ty = threadIdx.x >> 5;
  const int kb = blockIdx.y * 32, nb = blockIdx.x * 32;
#pragma unroll
  for (int i = 0; i < 4; i++)
    t[ty + i * 8][tx] = W[(size_t)(kb + ty + i * 8) * 1024 + nb + tx];
  __syncthreads();
#pragma unroll
  for (int i = 0; i < 4; i++)
    O[(size_t)(nb + ty + i * 8) * 1024 + kb + tx] = f2b(t[tx][ty + i * 8]);
}

// ---------------------------------------------------------------------------
// FAST projection GEMM (m97 structure): C = A(bf16 [4096,1024]) * W^T(bf16).
// z=0: Q head-major, PRE-SCALED by QSCALE. z=1: K head-major. z=2: V^T.
// ---------------------------------------------------------------------------
__global__ __launch_bounds__(256) void gemm_proj_bf16_kernel(
    const __bf16* __restrict__ A0, const __bf16* __restrict__ A1,
    const __bf16* __restrict__ A2, const __bf16* __restrict__ WT,
    __bf16* __restrict__ C0, __bf16* __restrict__ C1, __bf16* __restrict__ C2)
{
  const int z = blockIdx.y;
  const __bf16* A = (z == 0) ? A0 : (z == 1) ? A1 : A2;
  const __bf16* W = WT + (size_t)z * 1048576;
  __bf16* C = (z == 0) ? C0 : (z == 1) ? C1 : C2;
  const float osc = (z == 0) ? QSCALE : 1.0f;

  const int bid = blockIdx.x;
  const int t = (bid & 7) * 32 + (bid >> 3);
  const int mt = t >> 3, nt = t & 7;
  const int mbase = mt * 128, nbase = nt * 128;

  __shared__ __align__(16) __bf16 As[128][32];
  __shared__ __align__(16) __bf16 Bs[128][32];

  const int tid = threadIdx.x;
  const int wid = tid >> 6, lane = tid & 63;
  const int wr = wid >> 1, wc = wid & 1;
  const int lr = lane & 15, kg = lane >> 4;

  f32x4 acc[4][4] = {};

  const int srow = tid >> 2, scol = (tid & 3) * 8;
  const int wbase = tid & 192;

  for (int kb = 0; kb < 32; ++kb) {
    const int k0 = kb * 32;
    __syncthreads();
#pragma unroll
    for (int p = 0; p < 2; ++p) {
      const int r = srow + p * 64;
      gload_lds16(&A[(size_t)(mbase + r) * 1024 + k0 + scol],
                  (__bf16*)As + (size_t)(p * 256 + wbase) * 8);
      gload_lds16(&W[(size_t)(nbase + r) * 1024 + k0 + scol],
                  (__bf16*)Bs + (size_t)(p * 256 + wbase) * 8);
    }
    __syncthreads();

    bf16x8 af[4], bfr[4];
#pragma unroll
    for (int i = 0; i < 4; i++) af[i] = *(const bf16x8*)&As[wr * 64 + i * 16 + lr][kg * 8];
#pragma unroll
    for (int j = 0; j < 4; j++) bfr[j] = *(const bf16x8*)&Bs[wc * 64 + j * 16 + lr][kg * 8];
#pragma unroll
    for (int i = 0; i < 4; i++)
#pragma unroll
      for (int j = 0; j < 4; j++)
        acc[i][j] = MFMA(af[i], bfr[j], acc[i][j], 0, 0, 0);
  }

  if (z == 2) {
#pragma unroll
    for (int i = 0; i < 4; i++)
#pragma unroll
      for (int j = 0; j < 4; j++) {
        const int m0 = mbase + wr * 64 + i * 16 + kg * 4;
        const int n = nbase + wc * 64 + j * 16 + lr;
        const int b = m0 >> 11, s = m0 & 2047, h = n >> 6, dv = n & 63;
        bf16x4 w;
#pragma unroll
        for (int r = 0; r < 4; r++) w[r] = f2b(acc[i][j][r]);
        *(bf16x4*)&C[(((size_t)(b * 16 + h)) * 64 + dv) * 2048 + s] = w;
      }
  } else {
#pragma unroll
    for (int i = 0; i < 4; i++)
#pragma unroll
      for (int j = 0; j < 4; j++)
#pragma unroll
        for (int r = 0; r < 4; r++) {
          const int m = mbase + wr * 64 + i * 16 + kg * 4 + r;
          const int n = nbase + wc * 64 + j * 16 + lr;
          const int b = m >> 11, s = m & 2047, h = n >> 6, dk = n & 63;
          C[(((size_t)(b * 16 + h)) * 2048 + s) * 64 + dk] = f2b(acc[i][j][r] * osc);
        }
  }
}

// ---------------------------------------------------------------------------
// FALLBACK projection GEMM (fp32 A) — used if ws too small.
// ---------------------------------------------------------------------------
__global__ __launch_bounds__(256) void gemm_proj_f32_kernel(
    const float* __restrict__ A0, const float* __restrict__ A1,
    const float* __restrict__ A2, const __bf16* __restrict__ WT,
    __bf16* __restrict__ C0, __bf16* __restrict__ C1, __bf16* __restrict__ C2)
{
  const int z = blockIdx.y;
  const float* A = (z == 0) ? A0 : (z == 1) ? A1 : A2;
  const __bf16* W = WT + (size_t)z * 1048576;
  __bf16* C = (z == 0) ? C0 : (z == 1) ? C1 : C2;
  const float osc = (z == 0) ? QSCALE : 1.0f;

  const int mt = blockIdx.x >> 3, nt = blockIdx.x & 7;
  const int mbase = mt * 128, nbase = nt * 128;

  __shared__ __align__(16) __bf16 As[128][40];
  __shared__ __align__(16) __bf16 Bs[128][40];

  const int tid = threadIdx.x;
  const int wid = tid >> 6, lane = tid & 63;
  const int wr = wid >> 1, wc = wid & 1;
  const int lr = lane & 15, kg = lane >> 4;

  f32x4 acc[4][4] = {};
  const int arow = tid >> 3, ac0 = (tid & 7) * 4;

  for (int kb = 0; kb < 32; ++kb) {
    const int k0 = kb * 32;
#pragma unroll
    for (int p = 0; p < 4; ++p) {
      const int r = arow + p * 32;
      f32x4 av = *(const f32x4*)&A[(size_t)(mbase + r) * 1024 + k0 + ac0];
      bf16x4 cv = {f2b(av[0]), f2b(av[1]), f2b(av[2]), f2b(av[3])};
      *(bf16x4*)&As[r][ac0] = cv;
    }
#pragma unroll
    for (int p = 0; p < 2; ++p) {
      const int idx = p * 256 + tid;
      const int r = idx >> 2, c8 = (idx & 3) * 8;
      *(u32x4*)&Bs[r][c8] = *(const u32x4*)&W[(size_t)(nbase + r) * 1024 + k0 + c8];
    }
    __syncthreads();

    bf16x8 af[4], bfr[4];
#pragma unroll
    for (int i = 0; i < 4; i++) af[i] = *(const bf16x8*)&As[wr * 64 + i * 16 + lr][kg * 8];
#pragma unroll
    for (int j = 0; j < 4; j++) bfr[j] = *(const bf16x8*)&Bs[wc * 64 + j * 16 + lr][kg * 8];
#pragma unroll
    for (int i = 0; i < 4; i++)
#pragma unroll
      for (int j = 0; j < 4; j++)
        acc[i][j] = MFMA(af[i], bfr[j], acc[i][j], 0, 0, 0);
    __syncthreads();
  }

  if (z == 2) {
#pragma unroll
    for (int i = 0; i < 4; i++)
#pragma unroll
      for (int j = 0; j < 4; j++) {
        const int m0 = mbase + wr * 64 + i * 16 + kg * 4;
        const int n = nbase + wc * 64 + j * 16 + lr;
        const int b = m0 >> 11, s = m0 & 2047, h = n >> 6, dv = n & 63;
        bf16x4 w;
#pragma unroll
        for (int r = 0; r < 4; r++) w[r] = f2b(acc[i][j][r]);
        *(bf16x4*)&C[(((size_t)(b * 16 + h)) * 64 + dv) * 2048 + s] = w;
      }
  } else {
#pragma unroll
    for (int i = 0; i < 4; i++)
#pragma unroll
      for (int j = 0; j < 4; j++)
#pragma unroll
        for (int r = 0; r < 4; r++) {
          const int m = mbase + wr * 64 + i * 16 + kg * 4 + r;
          const int n = nbase + wc * 64 + j * 16 + lr;
          const int b = m >> 11, s = m & 2047, h = n >> 6, dk = n & 63;
          C[(((size_t)(b * 16 + h)) * 2048 + s) * 64 + dk] = f2b(acc[i][j][r] * osc);
        }
  }
}

// ---------------------------------------------------------------------------
// Causal flash attention v5.1 (v5 + branch-deferred row-max shfls).
// Q(pre-scaled)/K bf16 [B*H,2048,64]; V^T bf16 [B*H,64,2048].
// grid 1024: one 64-row q-block per block, qblk-descending within
// XCD-contiguous chunks (4 heads/XCD). block 256 (4 waves, 16 q-rows each).
// S^T = K Q^T; lane-local softmax; defer-max check uses PER-LANE max
// (__any makes it equivalent to the row-max check); the 2 cross-lane shfls
// run only inside the rare rescale branch. P via per-wave LDS bounce;
// PV = plain b128 V^T fragments. K/V dbuf, 1 barrier/iter.
// ---------------------------------------------------------------------------
__global__ __launch_bounds__(256) void attn_kernel(
    const __bf16* __restrict__ Qh, const __bf16* __restrict__ Kh,
    const __bf16* __restrict__ VTh, __bf16* __restrict__ AO)
{
  const int lin = blockIdx.x;
  const int l = (lin & 7) * 128 + (lin >> 3);  // XCD-contiguous (1024%8==0)
  const int bh = l >> 5;
  const int qblk = 31 - (l & 31);              // heavy blocks dispatch first
  const int b = bh >> 4, h = bh & 15;
  const __bf16* Qp = Qh + (size_t)bh * 2048 * 64;
  const __bf16* Kp = Kh + (size_t)bh * 2048 * 64;
  const __bf16* Vp = VTh + (size_t)bh * 64 * 2048;

  __shared__ __align__(16) __bf16 Ks[2][64][72];
  __shared__ __align__(16) __bf16 Vt[2][64][72];
  __shared__ __align__(16) __bf16 Ps[4][16][72];

  const int tid = threadIdx.x, wid = tid >> 6, lane = tid & 63;
  const int lr = lane & 15, kg = lane >> 4;
  const int sr0 = tid >> 3, sc0 = (tid & 7) * 8;

  const int qbase = qblk << 6;
  const int nkv = qblk + 1;
  const int wq = qbase + wid * 16;

  bf16x8 qf0 = *(const bf16x8*)&Qp[(size_t)(wq + lr) * 64 + kg * 8];
  bf16x8 qf1 = *(const bf16x8*)&Qp[(size_t)(wq + lr) * 64 + 32 + kg * 8];

  f32x4 ot[4] = {};
  float mrow = -1e30f, lsum = 0.f;   // lsum lane-partial; mrow row-uniform

  // stage tile 0
  u32x4 kr0 = *(const u32x4*)&Kp[(size_t)sr0 * 64 + sc0];
  u32x4 kr1 = *(const u32x4*)&Kp[(size_t)(sr0 + 32) * 64 + sc0];
  u32x4 vr0 = *(const u32x4*)&Vp[(size_t)sr0 * 2048 + sc0];
  u32x4 vr1 = *(const u32x4*)&Vp[(size_t)(sr0 + 32) * 2048 + sc0];
  *(u32x4*)&Ks[0][sr0][sc0] = kr0;
  *(u32x4*)&Ks[0][sr0 + 32][sc0] = kr1;
  *(u32x4*)&Vt[0][sr0][sc0] = vr0;
  *(u32x4*)&Vt[0][sr0 + 32][sc0] = vr1;

  int cur = 0;
  for (int t = 0; t < nkv; ++t) {
    const bool pre = (t + 1 < nkv);
    if (pre) {
      const int n0 = (t + 1) << 6;
      kr0 = *(const u32x4*)&Kp[(size_t)(n0 + sr0) * 64 + sc0];
      kr1 = *(const u32x4*)&Kp[(size_t)(n0 + sr0 + 32) * 64 + sc0];
      vr0 = *(const u32x4*)&Vp[(size_t)sr0 * 2048 + n0 + sc0];
      vr1 = *(const u32x4*)&Vp[(size_t)(sr0 + 32) * 2048 + n0 + sc0];
    }
    __syncthreads();

    // ---- S^T = K Q^T ----
    f32x4 st[4] = {};
    __builtin_amdgcn_s_setprio(1);
#pragma unroll
    for (int kvt = 0; kvt < 4; ++kvt) {
      bf16x8 kf0 = *(const bf16x8*)&Ks[cur][kvt * 16 + lr][kg * 8];
      bf16x8 kf1 = *(const bf16x8*)&Ks[cur][kvt * 16 + lr][32 + kg * 8];
      st[kvt] = MFMA(kf0, qf0, st[kvt], 0, 0, 0);
      st[kvt] = MFMA(kf1, qf1, st[kvt], 0, 0, 0);
    }
    __builtin_amdgcn_s_setprio(0);

    // ---- softmax (Q pre-scaled; log2 domain) ----
    float sv[16];
#pragma unroll
    for (int kvt = 0; kvt < 4; ++kvt)
#pragma unroll
      for (int r = 0; r < 4; ++r) sv[kvt * 4 + r] = st[kvt][r];
    if (t == nkv - 1) {  // diagonal tile: causal mask
      const int qidx = wq + lr;
      const int kvb = t << 6;
#pragma unroll
      for (int kvt = 0; kvt < 4; ++kvt)
#pragma unroll
        for (int r = 0; r < 4; ++r)
          if (kvb + kvt * 16 + kg * 4 + r > qidx) sv[kvt * 4 + r] = -1e30f;
    }
    // per-lane max only (cross-lane OR comes free from __any)
    float mx = fmaxf(fmaxf(sv[0], sv[1]), sv[2]);
    mx = fmaxf(fmaxf(mx, sv[3]), sv[4]);
    mx = fmaxf(fmaxf(mx, sv[5]), sv[6]);
    mx = fmaxf(fmaxf(mx, sv[7]), sv[8]);
    mx = fmaxf(fmaxf(mx, sv[9]), sv[10]);
    mx = fmaxf(fmaxf(mx, sv[11]), sv[12]);
    mx = fmaxf(fmaxf(mx, sv[13]), sv[14]);
    mx = fmaxf(mx, sv[15]);
    if (__any(mx > mrow + 8.f)) {      // defer-max: rescale only when needed
      // row-max shfls only on the rare rescale path
      mx = fmaxf(mx, __shfl_xor(mx, 16));
      mx = fmaxf(mx, __shfl_xor(mx, 32));
      const float mnew = fmaxf(mrow, mx);
      const float scl = exp2f(mrow - mnew);
      mrow = mnew;
      lsum *= scl;
#pragma unroll
      for (int dvt = 0; dvt < 4; ++dvt) ot[dvt] *= scl;
    }
#pragma unroll
    for (int kvt = 0; kvt < 4; ++kvt) {
      bf16x4 pk;
#pragma unroll
      for (int r = 0; r < 4; ++r) {
        const float p = exp2f(sv[kvt * 4 + r] - mrow);
        lsum += p;
        pk[r] = f2b(p);
      }
      *(bf16x4*)&Ps[wid][lr][kvt * 16 + kg * 4] = pk;
    }

    // ---- O^T += V^T P^T ----
#pragma unroll
    for (int h2 = 0; h2 < 2; ++h2) {
      bf16x8 pf = *(const bf16x8*)&Ps[wid][lr][h2 * 32 + kg * 8];
      __builtin_amdgcn_s_setprio(1);
#pragma unroll
      for (int dvt = 0; dvt < 4; ++dvt) {
        bf16x8 vf = *(const bf16x8*)&Vt[cur][dvt * 16 + lr][h2 * 32 + kg * 8];
        ot[dvt] = MFMA(vf, pf, ot[dvt], 0, 0, 0);
      }
      __builtin_amdgcn_s_setprio(0);
    }

    if (pre) {
      const int nb = cur ^ 1;
      *(u32x4*)&Ks[nb][sr0][sc0] = kr0;
      *(u32x4*)&Ks[nb][sr0 + 32][sc0] = kr1;
      *(u32x4*)&Vt[nb][sr0][sc0] = vr0;
      *(u32x4*)&Vt[nb][sr0 + 32][sc0] = vr1;
    }
    cur ^= 1;
  }

  // epilogue: combine lane-partial lsum across the row's 4 lanes, then store
  lsum += __shfl_xor(lsum, 16);
  lsum += __shfl_xor(lsum, 32);
  const float rl = 1.f / lsum;
  const int q = wq + lr;
#pragma unroll
  for (int dvt = 0; dvt < 4; ++dvt) {
    bf16x4 w;
#pragma unroll
    for (int r = 0; r < 4; ++r) w[r] = f2b(ot[dvt][r] * rl);
    *(bf16x4*)&AO[((size_t)(b * 2048 + q)) * 1024 + h * 64 + dvt * 16 + kg * 4] = w;
  }
}

// ---------------------------------------------------------------------------
// Output GEMM (m97 structure): out(fp32) = AO(bf16) * Wo^T(bf16).
// ---------------------------------------------------------------------------
__global__ __launch_bounds__(256) void gemm_out_kernel(
    const __bf16* __restrict__ A, const __bf16* __restrict__ WT,
    float* __restrict__ Out)
{
  const int bid = blockIdx.x;
  const int t = (bid & 7) * 32 + (bid >> 3);
  const int mt = t >> 3, nt = t & 7;
  const int mbase = mt * 128, nbase = nt * 128;

  __shared__ __align__(16) __bf16 As[128][32];
  __shared__ __align__(16) __bf16 Bs[128][32];

  const int tid = threadIdx.x;
  const int wid = tid >> 6, lane = tid & 63;
  const int wr = wid >> 1, wc = wid & 1;
  const int lr = lane & 15, kg = lane >> 4;

  f32x4 acc[4][4] = {};

  const int srow = tid >> 2, scol = (tid & 3) * 8;
  const int wbase = tid & 192;

  for (int kb = 0; kb < 32; ++kb) {
    const int k0 = kb * 32;
    __syncthreads();
#pragma unroll
    for (int p = 0; p < 2; ++p) {
      const int r = srow + p * 64;
      gload_lds16(&A[(size_t)(mbase + r) * 1024 + k0 + scol],
                  (__bf16*)As + (size_t)(p * 256 + wbase) * 8);
      gload_lds16(&WT[(size_t)(nbase + r) * 1024 + k0 + scol],
                  (__bf16*)Bs + (size_t)(p * 256 + wbase) * 8);
    }
    __syncthreads();

    bf16x8 af[4], bfr[4];
#pragma unroll
    for (int i = 0; i < 4; i++) af[i] = *(const bf16x8*)&As[wr * 64 + i * 16 + lr][kg * 8];
#pragma unroll
    for (int j = 0; j < 4; j++) bfr[j] = *(const bf16x8*)&Bs[wc * 64 + j * 16 + lr][kg * 8];
#pragma unroll
    for (int i = 0; i < 4; i++)
#pragma unroll
      for (int j = 0; j < 4; j++)
        acc[i][j] = MFMA(af[i], bfr[j], acc[i][j], 0, 0, 0);
  }

#pragma unroll
  for (int i = 0; i < 4; i++)
#pragma unroll
    for (int j = 0; j < 4; j++)
#pragma unroll
      for (int r = 0; r < 4; r++) {
        const int m = mbase + wr * 64 + i * 16 + kg * 4 + r;
        const int n = nbase + wc * 64 + j * 16 + lr;
        Out[(size_t)m * 1024 + n] = acc[i][j][r];
      }
}

// ---------------------------------------------------------------------------
extern "C" void kernel_launch(void* const* d_in, const int* in_sizes, int n_in,
                              void* d_out, int out_size, void* d_ws, size_t ws_size,
                              hipStream_t stream) {
  const float* Q  = (const float*)d_in[0];
  const float* K  = (const float*)d_in[1];
  const float* V  = (const float*)d_in[2];
  const float* Wq = (const float*)d_in[3];
  const float* Wk = (const float*)d_in[4];
  const float* Wv = (const float*)d_in[5];
  const float* Wo = (const float*)d_in[6];
  float* out = (float*)d_out;

  const size_t M4 = 4194304;
  __bf16* wT  = (__bf16*)d_ws;
  __bf16* qb  = wT + M4;
  __bf16* kb  = qb + M4;
  __bf16* vtb = kb + M4;

  const bool fast = ws_size >= (size_t)(28 * 1048576) * 2;  // 56 MiB

  __bf16* ao;
  if (fast) {
    __bf16* qa = vtb + M4;
    __bf16* ka = qa + M4;
    __bf16* va = ka + M4;
    ao = qa;
    prep_kernel<<<dim3(1024, 7), 256, 0, stream>>>(Wq, Wk, Wv, Wo, Q, K, V,
                                                   wT, qa, ka, va);
    gemm_proj_bf16_kernel<<<dim3(256, 3), 256, 0, stream>>>(qa, ka, va, wT,
                                                            qb, kb, vtb);
  } else {
    ao = vtb + M4;
    wtrans_kernel<<<dim3(32, 32, 4), 256, 0, stream>>>(Wq, Wk, Wv, Wo, wT);
    gemm_proj_f32_kernel<<<dim3(256, 3), 256, 0, stream>>>(Q, K, V, wT,
                                                           qb, kb, vtb);
  }

  attn_kernel<<<dim3(1024), 256, 0, stream>>>(qb, kb, vtb, ao);
  gemm_out_kernel<<<dim3(256), 256, 0, stream>>>(ao, wT + 3 * 1048576, out);
}